// Round 8
// baseline (485.154 us; speedup 1.0000x reference)
//
#include <hip/hip_runtime.h>
#include <stdint.h>

// Fixed problem geometry: N=3072 tokens, C=2048, H=16, hd=128, 4 x 768 segments
#define N_TOK  3072
#define C_DIM  2048
#define K3C    6144
#define NHEAD  16
#define HD     128
#define SEGLEN 768

typedef __attribute__((ext_vector_type(8))) short  short8;
typedef __attribute__((ext_vector_type(4))) float  f32x4;

__device__ __forceinline__ unsigned short f2bf(float f) {
  unsigned u = __builtin_bit_cast(unsigned, f);
  u += 0x7FFFu + ((u >> 16) & 1u);   // RNE
  return (unsigned short)(u >> 16);
}
__device__ __forceinline__ float bf2f(unsigned short h) {
  unsigned u = ((unsigned)h) << 16;
  return __builtin_bit_cast(float, u);
}
__device__ __forceinline__ void gload_lds16(const void* g, void* l) {
  __builtin_amdgcn_global_load_lds(
      (const __attribute__((address_space(1))) unsigned int*)g,
      (__attribute__((address_space(3))) unsigned int*)l, 16, 0, 0);
}

// ---------------- K0: f32 -> bf16 casts (x, qkv_w, proj_w) ----------------
#define XB_ELEMS    (3072L*2048L)
#define WQKV_ELEMS  (6144L*2048L)
#define WPROJ_ELEMS (2048L*2048L)
__global__ __launch_bounds__(256) void cast_bf16_kernel(
    const float* __restrict__ x, const float* __restrict__ wqkv,
    const float* __restrict__ wproj, unsigned short* __restrict__ xb,
    unsigned short* __restrict__ wqkvb, unsigned short* __restrict__ wprojb) {
  long t = (long)blockIdx.x * 256 + threadIdx.x;
  long i = t * 8;
  const float* src; unsigned short* dst; long off;
  if (i < XB_ELEMS)                   { src = x;     dst = xb;     off = i; }
  else if (i < XB_ELEMS + WQKV_ELEMS) { src = wqkv;  dst = wqkvb;  off = i - XB_ELEMS; }
  else                                { src = wproj; dst = wprojb; off = i - XB_ELEMS - WQKV_ELEMS; }
  f32x4 a = *(const f32x4*)(src + off);
  f32x4 b = *(const f32x4*)(src + off + 4);
  short8 o;
  #pragma unroll
  for (int k = 0; k < 4; ++k) { o[k] = (short)f2bf(a[k]); o[k+4] = (short)f2bf(b[k]); }
  *(short8*)(dst + off) = o;
}

// ---------------- K1/K5: 128x128 tile, 4-deep ring-pipelined GEMM ---------
// C = A * B^T + bias. A[M][K], B[N][K] bf16 row-major. M%128==0, N%128==0,
// K%32==0, K>=128. 256 threads = 4 waves (2Mx2N), per-wave 64x64 output.
// LDS 64 KiB: sH[4 ring bufs][2 mats][4 kchunks][128 rows][8 bf16]
//   (one buf = one BK=32 K-tile of A+B = 16 KiB). 2 blocks/CU co-resident.
// DEEP PIPELINE (the R6/R7 fix): tile p is STAGED at phase p-3 and WAITED
// at phase p via vmcnt(8) (per-wave: 12 outstanding -> 8 keeps tiles
// p+1,p+2 in flight, lands tile p). 3 phases x ~300-600cy covers HBM/L3
// latency; vmcnt never drains to 0 in the main loop.
// Per-phase (ONE barrier): VM8 ; s_barrier ; 8x ds_read_b128 (conflict-free,
// 16B/lane stride) ; stage tile p+3 (4 gloads/wave) ; lgkmcnt(0) ; 16 MFMA.
// Hazards: buffer b re-staged at phase p+3 = 2 phases after its last read
// (lgkmcnt(0)+barrier in between). Reads of tile p are covered by own VM8
// before the barrier; other waves' chunks by their VM8 + the barrier.
#define VM8 asm volatile("s_waitcnt vmcnt(8)" ::: "memory");
#define VM4 asm volatile("s_waitcnt vmcnt(4)" ::: "memory");
#define VM0 asm volatile("s_waitcnt vmcnt(0)" ::: "memory");

// wave wv stages chunks j=wv*4+q (q=0..3): mat=j>>3, kc=w1*2+(q>>1), half=q&1
#define STAGE3(b, t) do { \
  const size_t _ko = (size_t)(t)*32 + w1*16; \
  gload_lds16(R0 + _ko,     dB + (size_t)(b)*16384);        \
  gload_lds16(R1 + _ko,     dB + (size_t)(b)*16384 + 1024); \
  gload_lds16(R0 + _ko + 8, dB + (size_t)(b)*16384 + 2048); \
  gload_lds16(R1 + _ko + 8, dB + (size_t)(b)*16384 + 3072); \
} while (0)

#define PH(b, WAIT, STAGES) do { \
  WAIT \
  __builtin_amdgcn_s_barrier(); \
  __builtin_amdgcn_sched_barrier(0); \
  short8 aF[4], bF[4]; \
  _Pragma("unroll") \
  for (int m = 0; m < 4; ++m) \
    aF[m] = *(const short8*)&sH[b][0][lh][wr*64 + m*16 + lr][0]; \
  _Pragma("unroll") \
  for (int n = 0; n < 4; ++n) \
    bF[n] = *(const short8*)&sH[b][1][lh][wc*64 + n*16 + lr][0]; \
  STAGES \
  asm volatile("s_waitcnt lgkmcnt(0)" ::: "memory"); \
  __builtin_amdgcn_sched_barrier(0); \
  __builtin_amdgcn_s_setprio(1); \
  _Pragma("unroll") \
  for (int m = 0; m < 4; ++m) { \
    _Pragma("unroll") \
    for (int n = 0; n < 4; ++n) \
      acc[m][n] = __builtin_amdgcn_mfma_f32_16x16x32_bf16(aF[m], bF[n], acc[m][n], 0, 0, 0); \
  } \
  __builtin_amdgcn_s_setprio(0); \
  __builtin_amdgcn_sched_barrier(0); \
} while (0)

template<bool OUTF32>
__global__ __launch_bounds__(256, 3) void gemmv3(
    const unsigned short* __restrict__ A, const unsigned short* __restrict__ B,
    const float* __restrict__ bias, void* __restrict__ Cout,
    int N, int K_) {
  __shared__ __align__(16) unsigned short sH[4][2][4][128][8];   // 64 KiB
  char* ldsB = (char*)&sH[0][0][0][0][0];
  const int tid = threadIdx.x;
  const int wv = tid >> 6, l = tid & 63, lr = l & 15, lh = l >> 4;
  const int wr = wv >> 1, wc = wv & 1, w1 = wv & 1;

  // bijective XCD swizzle (nwg % 8 == 0 for both call sites)
  const int nwg = gridDim.x * gridDim.y;
  const int bid = blockIdx.y * gridDim.x + blockIdx.x;
  const int swz = (bid & 7) * (nwg >> 3) + (bid >> 3);
  const int bx = swz % gridDim.x, by = swz / gridDim.x;
  const long row0 = (long)by * 128;
  const long col0 = (long)bx * 128;

  // wave-uniform staging bases: waves 0,1 -> A; waves 2,3 -> B
  const unsigned short* SBase = (wv & 2) ? (B + col0 * K_) : (A + row0 * K_);
  const unsigned short* R0 = SBase + (size_t)l * K_;
  const unsigned short* R1 = R0 + (size_t)64 * K_;
  char* dB = ldsB + (size_t)wv * 4096;

  f32x4 acc[4][4] = {};

  STAGE3(0, 0); STAGE3(1, 1); STAGE3(2, 2);   // 12 loads/wave in flight

  const int NT = K_ >> 5;
  int p = 0;
  #pragma unroll 1
  for (; p < NT - 3; ++p) {
    PH((p & 3), VM8, STAGE3(((p + 3) & 3), p + 3););
  }
  PH((p & 3), VM8, ); ++p;
  PH((p & 3), VM4, ); ++p;
  PH((p & 3), VM0, );

  // epilogue: D[row = lh*4+r][col = lr] per 16x16 frag
  #pragma unroll
  for (int n = 0; n < 4; ++n) {
    const long col = col0 + wc*64 + n*16 + lr;
    const float bv = bias[col];
    #pragma unroll
    for (int m = 0; m < 4; ++m) {
      const long rb = row0 + wr*64 + m*16 + lh*4;
      #pragma unroll
      for (int r = 0; r < 4; ++r) {
        float val = acc[m][n][r] + bv;
        if constexpr (OUTF32) ((float*)Cout)[(rb + r)*N + col] = val;
        else ((unsigned short*)Cout)[(rb + r)*N + col] = f2bf(val);
      }
    }
  }
}

// ---------------- K2: RoPE in-place on q,k halves of qkv ------------------
__global__ __launch_bounds__(256) void rope_kernel(
    unsigned short* __restrict__ qkv, const float* __restrict__ fcos,
    const float* __restrict__ fsin) {
  long t = (long)blockIdx.x * 256 + threadIdx.x;
  int n  = (int)(t >> 9);
  int col = (int)(t & 511) * 8;
  int j0 = (col & 127) >> 1;
  unsigned short* p = qkv + (long)n * K3C + col;
  short8 v = *(short8*)p;
  f32x4 vc = *(const f32x4*)(fcos + n*64 + j0);
  f32x4 vs = *(const f32x4*)(fsin + n*64 + j0);
  short8 o;
  #pragma unroll
  for (int i = 0; i < 4; ++i) {
    float re = bf2f((unsigned short)v[2*i]);
    float im = bf2f((unsigned short)v[2*i+1]);
    float c = vc[i], s = vs[i];
    o[2*i]   = (short)f2bf(re*c - im*s);
    o[2*i+1] = (short)f2bf(re*s + im*c);
  }
  *(short8*)p = o;
}

// ---------------- K3: transpose V -> vT[h][d][n] --------------------------
__global__ __launch_bounds__(256) void transpose_v_kernel(
    const unsigned short* __restrict__ qkv, unsigned short* __restrict__ vT) {
  __shared__ unsigned short sT[64*64];
  int bidx = blockIdx.x;
  const int nb = (bidx % 48) * 64; bidx /= 48;
  const int db = (bidx & 1) * 64;  bidx >>= 1;
  const int h  = bidx;
  const int tid = threadIdx.x;
  #pragma unroll
  for (int p = 0; p < 2; ++p) {
    int ch = tid + p*256;
    int row = ch >> 3, c8 = ch & 7;
    f32x4 val = *(const f32x4*)(qkv + (long)(nb + row)*K3C + 4096 + h*HD + db + c8*8);
    int off = (row*128 + c8*16) ^ ((row & 7) << 4);
    *(f32x4*)((char*)sT + off) = val;
  }
  __syncthreads();
  #pragma unroll
  for (int p = 0; p < 2; ++p) {
    int ch = tid + p*256;
    int drow = ch >> 3, nc = ch & 7;
    short8 tv;
    #pragma unroll
    for (int j = 0; j < 8; ++j) {
      int nn = nc*8 + j;
      int off = (nn*128 + drow*2) ^ ((nn & 7) << 4);
      tv[j] = *(const short*)((const char*)sT + off);
    }
    *(short8*)(vT + ((long)h*HD + db + drow)*N_TOK + nb + nc*8) = tv;
  }
}

// ---------------- K4: block-diagonal flash attention ----------------------
__global__ __launch_bounds__(256) void attn_kernel(
    const unsigned short* __restrict__ qkv, const unsigned short* __restrict__ vT,
    unsigned short* __restrict__ attb) {
  __shared__ unsigned short sK [64*128];
  __shared__ unsigned short sVT[128*64];
  __shared__ unsigned short sP [4][16*72];
  const int tid = threadIdx.x;
  const int w = tid >> 6, l = tid & 63, lr = l & 15, lh = l >> 4;
  int bidx = blockIdx.x;
  const int qt = bidx % 12; bidx /= 12;
  const int h  = bidx & 15; bidx >>= 4;
  const int s  = bidx;
  const int n0 = s*SEGLEN + qt*64;
  const float scale = 0.08838834764831845f;
  const float LOG2E = 1.4426950408889634f;

  short8 aq[4];
  {
    const unsigned short* qrow = qkv + (long)(n0 + w*16 + lr)*K3C + h*HD;
    #pragma unroll
    for (int c = 0; c < 4; ++c) aq[c] = *(const short8*)(qrow + c*32 + lh*8);
  }
  f32x4 o[8] = {};
  float m_r[4] = {-1e30f, -1e30f, -1e30f, -1e30f};
  float l_r[4] = {0.f, 0.f, 0.f, 0.f};

  for (int kt = 0; kt < 12; ++kt) {
    const int kb = s*SEGLEN + kt*64;
    __syncthreads();
    #pragma unroll
    for (int p = 0; p < 4; ++p) {
      int ch = (p*4 + w)*64 + l;
      int key = ch >> 4;
      int kc  = (ch & 15) ^ (key & 7);
      gload_lds16(qkv + (long)(kb + key)*K3C + C_DIM + h*HD + kc*8,
                  (char*)sK + (size_t)(p*4 + w)*1024);
      int d   = ch >> 3;
      int kc2 = (ch & 7) ^ (d & 7);
      gload_lds16(vT + ((long)h*HD + d)*N_TOK + kb + kc2*8,
                  (char*)sVT + (size_t)(p*4 + w)*1024);
    }
    __syncthreads();

    f32x4 sacc[4] = {};
    #pragma unroll
    for (int kd = 0; kd < 4; ++kd)
      #pragma unroll
      for (int kf = 0; kf < 4; ++kf) {
        int key = kf*16 + lr;
        int off = (key*256 + kd*64 + lh*16) ^ ((key & 7) << 4);
        short8 bk = *(const short8*)((const char*)sK + off);
        sacc[kf] = __builtin_amdgcn_mfma_f32_16x16x32_bf16(aq[kd], bk, sacc[kf], 0, 0, 0);
      }

    float alpha[4];
    #pragma unroll
    for (int r = 0; r < 4; ++r) {
      float v0 = fmaxf(fmaxf(sacc[0][r], sacc[1][r]), fmaxf(sacc[2][r], sacc[3][r]));
      #pragma unroll
      for (int sh = 1; sh < 16; sh <<= 1) v0 = fmaxf(v0, __shfl_xor(v0, sh, 64));
      float pm = v0 * scale;
      float mn = fmaxf(m_r[r], pm);
      alpha[r] = __builtin_exp2f((m_r[r] - mn) * LOG2E);
      m_r[r] = mn;
    }
    float rsum[4] = {0.f, 0.f, 0.f, 0.f};
    #pragma unroll
    for (int kf = 0; kf < 4; ++kf)
      #pragma unroll
      for (int r = 0; r < 4; ++r) {
        float pv = __builtin_exp2f((sacc[kf][r]*scale - m_r[r]) * LOG2E);
        rsum[r] += pv;
        sP[w][(lh*4 + r)*72 + kf*16 + lr] = f2bf(pv);
      }
    #pragma unroll
    for (int r = 0; r < 4; ++r) {
      float t = rsum[r];
      #pragma unroll
      for (int sh = 1; sh < 16; sh <<= 1) t += __shfl_xor(t, sh, 64);
      l_r[r] = l_r[r]*alpha[r] + t;
    }
    #pragma unroll
    for (int nf = 0; nf < 8; ++nf)
      #pragma unroll
      for (int r = 0; r < 4; ++r) o[nf][r] *= alpha[r];

    #pragma unroll
    for (int ks = 0; ks < 2; ++ks) {
      short8 ap = *(const short8*)&sP[w][lr*72 + ks*32 + lh*8];
      #pragma unroll
      for (int nf = 0; nf < 8; ++nf) {
        int d = nf*16 + lr;
        int off = (d*128 + ks*64 + lh*16) ^ ((d & 7) << 4);
        short8 bv = *(const short8*)((const char*)sVT + off);
        o[nf] = __builtin_amdgcn_mfma_f32_16x16x32_bf16(ap, bv, o[nf], 0, 0, 0);
      }
    }
  }

  #pragma unroll
  for (int r = 0; r < 4; ++r) {
    float inv = 1.0f / l_r[r];
    int n = n0 + w*16 + lh*4 + r;
    unsigned short* orow = attb + (long)n*C_DIM + h*HD;
    #pragma unroll
    for (int nf = 0; nf < 8; ++nf) orow[nf*16 + lr] = f2bf(o[nf][r] * inv);
  }
}

// ---------------- launch ---------------------------------------------------
extern "C" void kernel_launch(void* const* d_in, const int* in_sizes, int n_in,
                              void* d_out, int out_size, void* d_ws, size_t ws_size,
                              hipStream_t stream) {
  (void)in_sizes; (void)n_in; (void)out_size; (void)ws_size;
  const float* x      = (const float*)d_in[0];
  const float* fcos   = (const float*)d_in[1];
  const float* fsin   = (const float*)d_in[2];
  const float* qkv_w  = (const float*)d_in[3];
  const float* qkv_b  = (const float*)d_in[4];
  const float* proj_w = (const float*)d_in[5];
  const float* proj_b = (const float*)d_in[6];

  char* ws = (char*)d_ws;
  unsigned short* xb     = (unsigned short*)(ws + 0L);
  unsigned short* wqkvb  = (unsigned short*)(ws + 12582912L);
  unsigned short* wprojb = (unsigned short*)(ws + 37748736L);
  unsigned short* qkvb   = (unsigned short*)(ws + 46137344L);
  unsigned short* vT     = (unsigned short*)(ws + 83886080L);
  unsigned short* attb   = xb;               // alias: x dead after QKV GEMM

  cast_bf16_kernel<<<11264, 256, 0, stream>>>(x, qkv_w, proj_w, xb, wqkvb, wprojb);
  gemmv3<false><<<dim3(48, 24), 256, 0, stream>>>(xb, wqkvb, qkv_b, qkvb, 6144, 2048);
  rope_kernel<<<6144, 256, 0, stream>>>(qkvb, fcos, fsin);
  transpose_v_kernel<<<1536, 256, 0, stream>>>(qkvb, vT);
  attn_kernel<<<768, 256, 0, stream>>>(qkvb, vT, attb);
  gemmv3<true><<<dim3(16, 24), 256, 0, stream>>>(attb, wprojb, proj_b, d_out, 2048, 2048);
}